// Round 2
// baseline (462.872 us; speedup 1.0000x reference)
//
#include <hip/hip_runtime.h>

// CompositeValueNoise with spatial counting-sort for gather locality.
// Pipeline: memset(hist) -> histogram(4096 buckets = V16 cells) -> 1-block
// exclusive scan -> scatter points into d_ws sorted by bucket (AoS float4
// {x,y,z,bitcast(orig_idx)}) -> main gather kernel over sorted points with
// XCD-contiguous block swizzle, scattered float4 out-write.

#define NBUCKETS 4096            // 16^3
#define SCAN_THREADS 256
#define BINS_PER_THREAD (NBUCKETS / SCAN_THREADS)   // 16

__device__ __forceinline__ int bucket_of(float px, float py, float pz) {
    int ix = (int)floorf(fmodf(px * 16.0f, 16.0f));
    int iy = (int)floorf(fmodf(py * 16.0f, 16.0f));
    int iz = (int)floorf(fmodf(pz * 16.0f, 16.0f));
    ix = min(max(ix, 0), 15);
    iy = min(max(iy, 0), 15);
    iz = min(max(iz, 0), 15);
    return (ix * 16 + iy) * 16 + iz;
}

__global__ void __launch_bounds__(256)
cvn_hist_kernel(const float* __restrict__ x, int* __restrict__ hist, int n) {
    int i = blockIdx.x * blockDim.x + threadIdx.x;
    if (i >= n) return;
    int b = bucket_of(x[3 * i], x[3 * i + 1], x[3 * i + 2]);
    atomicAdd(&hist[b], 1);
}

__global__ void __launch_bounds__(SCAN_THREADS)
cvn_scan_kernel(int* __restrict__ hist) {
    __shared__ int part[SCAN_THREADS];
    int t = threadIdx.x;
    int base = t * BINS_PER_THREAD;
    int v[BINS_PER_THREAD];
    int s = 0;
    #pragma unroll
    for (int k = 0; k < BINS_PER_THREAD; ++k) {
        int tmp = hist[base + k];
        v[k] = s;
        s += tmp;
    }
    part[t] = s;
    __syncthreads();
    // Hillis-Steele inclusive scan over partials.
    for (int off = 1; off < SCAN_THREADS; off <<= 1) {
        int val = 0;
        if (t >= off) val = part[t - off];
        __syncthreads();
        if (t >= off) part[t] += val;
        __syncthreads();
    }
    int chunk_off = (t == 0) ? 0 : part[t - 1];
    #pragma unroll
    for (int k = 0; k < BINS_PER_THREAD; ++k)
        hist[base + k] = chunk_off + v[k];
}

__global__ void __launch_bounds__(256)
cvn_scatter_kernel(const float* __restrict__ x, int* __restrict__ cursor,
                   float4* __restrict__ sorted, int n) {
    int i = blockIdx.x * blockDim.x + threadIdx.x;
    if (i >= n) return;
    float px = x[3 * i], py = x[3 * i + 1], pz = x[3 * i + 2];
    int b = bucket_of(px, py, pz);
    int pos = atomicAdd(&cursor[b], 1);
    sorted[pos] = make_float4(px, py, pz, __int_as_float(i));
}

__device__ __forceinline__ float4 lerp4(float4 a, float4 b, float w) {
    return make_float4(a.x + w * (b.x - a.x),
                       a.y + w * (b.y - a.y),
                       a.z + w * (b.z - a.z),
                       a.w + w * (b.w - a.w));
}

template <int RES>
__device__ __forceinline__ float4 level_val(const float4* __restrict__ V,
                                            float px, float py, float pz) {
    constexpr int S = RES + 1;
    float xs = fmodf(px * (float)RES, (float)RES);
    float ys = fmodf(py * (float)RES, (float)RES);
    float zs = fmodf(pz * (float)RES, (float)RES);
    float fx = floorf(xs), fy = floorf(ys), fz = floorf(zs);
    float tx = xs - fx, ty = ys - fy, tz = zs - fz;
    int ix = (int)fx, iy = (int)fy, iz = (int)fz;

    float wx = (3.0f - 2.0f * tx) * tx * tx;
    float wy = (3.0f - 2.0f * ty) * ty * ty;
    float wz = (3.0f - 2.0f * tz) * tz * tz;

    int base = (ix * S + iy) * S + iz;
    const float4* p0 = V + base;
    const float4* p1 = p0 + S * S;

    float4 c000 = p0[0];
    float4 c001 = p0[1];
    float4 c010 = p0[S];
    float4 c011 = p0[S + 1];
    float4 c100 = p1[0];
    float4 c101 = p1[1];
    float4 c110 = p1[S];
    float4 c111 = p1[S + 1];

    float4 m00 = lerp4(c000, c100, wx);
    float4 m01 = lerp4(c001, c101, wx);
    float4 m10 = lerp4(c010, c110, wx);
    float4 m11 = lerp4(c011, c111, wx);
    float4 n0  = lerp4(m00, m10, wy);
    float4 n1  = lerp4(m01, m11, wy);
    return lerp4(n0, n1, wz);
}

__device__ __forceinline__ float4 composite(const float4* __restrict__ V16,
                                            const float4* __restrict__ V32,
                                            const float4* __restrict__ V64,
                                            const float4* __restrict__ V128,
                                            float px, float py, float pz) {
    float4 acc = level_val<16>(V16, px, py, pz);
    float4 v;
    v = level_val<32>(V32, px, py, pz);
    acc.x += 0.5f * v.x; acc.y += 0.5f * v.y; acc.z += 0.5f * v.z; acc.w += 0.5f * v.w;
    v = level_val<64>(V64, px, py, pz);
    acc.x += 0.25f * v.x; acc.y += 0.25f * v.y; acc.z += 0.25f * v.z; acc.w += 0.25f * v.w;
    v = level_val<128>(V128, px, py, pz);
    acc.x += 0.125f * v.x; acc.y += 0.125f * v.y; acc.z += 0.125f * v.z; acc.w += 0.125f * v.w;
    return acc;
}

// Main gather over sorted points. Block swizzle: round-robin dispatch maps
// blockIdx%8 to XCDs, so give each XCD a contiguous sorted (spatial) range.
__global__ void __launch_bounds__(256)
cvn_sorted_kernel(const float4* __restrict__ sorted,
                  const float4* __restrict__ V16,
                  const float4* __restrict__ V32,
                  const float4* __restrict__ V64,
                  const float4* __restrict__ V128,
                  float4* __restrict__ out, int n, int nblocks) {
    int nb8 = nblocks >> 3;  // nblocks is a multiple of 8
    int c = (blockIdx.x & 7) * nb8 + (blockIdx.x >> 3);
    int j = c * 256 + (int)threadIdx.x;
    if (j >= n) return;

    float4 p = sorted[j];
    float4 acc = composite(V16, V32, V64, V128, p.x, p.y, p.z);
    out[__float_as_int(p.w)] = acc;
}

// Fallback: direct unsorted kernel (R1 baseline) if ws too small.
__global__ void __launch_bounds__(256)
cvn_direct_kernel(const float* __restrict__ x,
                  const float4* __restrict__ V16,
                  const float4* __restrict__ V32,
                  const float4* __restrict__ V64,
                  const float4* __restrict__ V128,
                  float4* __restrict__ out, int n) {
    int i = blockIdx.x * blockDim.x + threadIdx.x;
    if (i >= n) return;
    float px = x[3 * i], py = x[3 * i + 1], pz = x[3 * i + 2];
    out[i] = composite(V16, V32, V64, V128, px, py, pz);
}

extern "C" void kernel_launch(void* const* d_in, const int* in_sizes, int n_in,
                              void* d_out, int out_size, void* d_ws, size_t ws_size,
                              hipStream_t stream) {
    const float*  x    = (const float*)d_in[0];
    const float4* V16  = (const float4*)d_in[1];
    const float4* V32  = (const float4*)d_in[2];
    const float4* V64  = (const float4*)d_in[3];
    const float4* V128 = (const float4*)d_in[4];
    float4* out = (float4*)d_out;

    int n = in_sizes[0] / 3;
    int block = 256;
    int grid = (n + block - 1) / block;

    size_t need = (size_t)NBUCKETS * sizeof(int) + (size_t)n * sizeof(float4);
    if (ws_size >= need) {
        int*    cursor = (int*)d_ws;
        float4* sorted = (float4*)((char*)d_ws + NBUCKETS * sizeof(int));

        hipMemsetAsync(cursor, 0, NBUCKETS * sizeof(int), stream);
        cvn_hist_kernel<<<grid, block, 0, stream>>>(x, cursor, n);
        cvn_scan_kernel<<<1, SCAN_THREADS, 0, stream>>>(cursor);
        cvn_scatter_kernel<<<grid, block, 0, stream>>>(x, cursor, sorted, n);

        int nblocks = ((grid + 7) / 8) * 8;  // pad to multiple of 8 for swizzle
        cvn_sorted_kernel<<<nblocks, block, 0, stream>>>(
            sorted, V16, V32, V64, V128, out, n, nblocks);
    } else {
        cvn_direct_kernel<<<grid, block, 0, stream>>>(
            x, V16, V32, V64, V128, out, n);
    }
}

// Round 3
// 349.863 us; speedup vs baseline: 1.3230x; 1.3230x over previous
//
#include <hip/hip_runtime.h>

// CompositeValueNoise, R3: atomic-free 16^3 counting sort with coalesced
// writes everywhere. Pipeline:
//   hist (per-block bucket counts -> P[b][q])
//   colscan (per-bucket exclusive prefix over blocks, totals -> T)
//   totscan (exclusive scan of T in place)
//   scatter (LDS-binned: coalesced bucket-sorted payload runs + rank[i])
//   main (sorted coalesced read, L1-resident gathers, coalesced tmp write)
//   permute (out[i] = tmp[rank[i]]: random LLC reads, coalesced writes)

#define BUCKETS 4096          // 16^3
#define PTS_PER_BLK 4096
#define SC_THREADS 1024
#define SC_PPT (PTS_PER_BLK / SC_THREADS)   // 4
#define H_THREADS 256
#define H_PPT (PTS_PER_BLK / H_THREADS)     // 16

__device__ __forceinline__ int bucket_of(float px, float py, float pz) {
    int ix = min(max((int)(px * 16.0f), 0), 15);
    int iy = min(max((int)(py * 16.0f), 0), 15);
    int iz = min(max((int)(pz * 16.0f), 0), 15);
    return (ix * 16 + iy) * 16 + iz;
}

__global__ void __launch_bounds__(H_THREADS)
cvn_hist(const float* __restrict__ x, int* __restrict__ P, int n) {
    __shared__ int cnt[BUCKETS];
    int t = threadIdx.x;
    for (int q = t; q < BUCKETS; q += H_THREADS) cnt[q] = 0;
    __syncthreads();
    int base = blockIdx.x * PTS_PER_BLK;
    for (int k = 0; k < H_PPT; ++k) {
        int i = base + k * H_THREADS + t;
        if (i < n)
            atomicAdd(&cnt[bucket_of(x[3 * i], x[3 * i + 1], x[3 * i + 2])], 1);
    }
    __syncthreads();
    int* Pb = P + (size_t)blockIdx.x * BUCKETS;
    for (int q = t; q < BUCKETS; q += H_THREADS) Pb[q] = cnt[q];
}

// Per-bucket exclusive prefix over blocks (in place); totals to T.
__global__ void __launch_bounds__(256)
cvn_colscan(int* __restrict__ P, int* __restrict__ T, int nblk) {
    int q = blockIdx.x * 256 + threadIdx.x;   // 0..4095
    int acc = 0;
    for (int b = 0; b < nblk; ++b) {
        int v = P[(size_t)b * BUCKETS + q];
        P[(size_t)b * BUCKETS + q] = acc;
        acc += v;
    }
    T[q] = acc;
}

// Exclusive scan of T[4096] in place. One block of 256 threads.
__global__ void __launch_bounds__(256)
cvn_totscan(int* __restrict__ T) {
    __shared__ int part[256];
    int t = threadIdx.x;
    int base = t * 16;
    int v[16];
    int s = 0;
    #pragma unroll
    for (int k = 0; k < 16; ++k) { int tmp = T[base + k]; v[k] = s; s += tmp; }
    part[t] = s;
    __syncthreads();
    for (int off = 1; off < 256; off <<= 1) {
        int val = (t >= off) ? part[t - off] : 0;
        __syncthreads();
        if (t >= off) part[t] += val;
        __syncthreads();
    }
    int ex = (t == 0) ? 0 : part[t - 1];
    #pragma unroll
    for (int k = 0; k < 16; ++k) T[base + k] = ex + v[k];
}

__global__ void __launch_bounds__(SC_THREADS)
cvn_scatter(const float* __restrict__ x, const int* __restrict__ OFF,
            const int* __restrict__ Texcl, float4* __restrict__ sorted,
            int* __restrict__ rank, int n, int write_rank) {
    __shared__ int cnt[BUCKETS];            // counts -> block-local excl scan
    __shared__ int place[BUCKETS];
    __shared__ float4 payload[PTS_PER_BLK]; // 64 KB
    __shared__ unsigned short bkt[PTS_PER_BLK];
    __shared__ int part[SC_THREADS];
    int t = threadIdx.x, b = blockIdx.x;
    int base = b * PTS_PER_BLK;
    for (int q = t; q < BUCKETS; q += SC_THREADS) { cnt[q] = 0; place[q] = 0; }
    __syncthreads();

    float px[SC_PPT], py[SC_PPT], pz[SC_PPT];
    int qq[SC_PPT];
    #pragma unroll
    for (int k = 0; k < SC_PPT; ++k) {
        int i = base + k * SC_THREADS + t;
        if (i < n) {
            px[k] = x[3 * i]; py[k] = x[3 * i + 1]; pz[k] = x[3 * i + 2];
            qq[k] = bucket_of(px[k], py[k], pz[k]);
            atomicAdd(&cnt[qq[k]], 1);
        } else qq[k] = -1;
    }
    __syncthreads();

    // Block-local exclusive scan of cnt[4096]: thread t owns bins 4t..4t+3.
    {
        int v[4];
        int s = 0;
        #pragma unroll
        for (int k = 0; k < 4; ++k) { v[k] = s; s += cnt[4 * t + k]; }
        part[t] = s;
        __syncthreads();
        for (int off = 1; off < SC_THREADS; off <<= 1) {
            int val = (t >= off) ? part[t - off] : 0;
            __syncthreads();
            if (t >= off) part[t] += val;
            __syncthreads();
        }
        int ex = (t == 0) ? 0 : part[t - 1];
        #pragma unroll
        for (int k = 0; k < 4; ++k) cnt[4 * t + k] = ex + v[k];
    }
    __syncthreads();

    const int* OFFb = OFF + (size_t)b * BUCKETS;
    #pragma unroll
    for (int k = 0; k < SC_PPT; ++k) {
        if (qq[k] >= 0) {
            int q = qq[k];
            int lp = atomicAdd(&place[q], 1);
            int slot = cnt[q] + lp;
            int i = base + k * SC_THREADS + t;
            payload[slot] = make_float4(px[k], py[k], pz[k], __int_as_float(i));
            bkt[slot] = (unsigned short)q;
            if (write_rank) rank[i] = Texcl[q] + OFFb[q] + lp;
        }
    }
    __syncthreads();

    int total = min(n - base, PTS_PER_BLK);
    #pragma unroll
    for (int k = 0; k < SC_PPT; ++k) {
        int j = k * SC_THREADS + t;
        if (j < total) {
            int q = bkt[j];
            sorted[Texcl[q] + OFFb[q] + (j - cnt[q])] = payload[j];
        }
    }
}

__device__ __forceinline__ float4 lerp4(float4 a, float4 b, float w) {
    return make_float4(a.x + w * (b.x - a.x),
                       a.y + w * (b.y - a.y),
                       a.z + w * (b.z - a.z),
                       a.w + w * (b.w - a.w));
}

template <int RES>
__device__ __forceinline__ float4 level_val(const float4* __restrict__ V,
                                            float px, float py, float pz) {
    constexpr int S = RES + 1;
    float xs = fmodf(px * (float)RES, (float)RES);
    float ys = fmodf(py * (float)RES, (float)RES);
    float zs = fmodf(pz * (float)RES, (float)RES);
    float fx = floorf(xs), fy = floorf(ys), fz = floorf(zs);
    float tx = xs - fx, ty = ys - fy, tz = zs - fz;
    int ix = (int)fx, iy = (int)fy, iz = (int)fz;

    float wx = (3.0f - 2.0f * tx) * tx * tx;
    float wy = (3.0f - 2.0f * ty) * ty * ty;
    float wz = (3.0f - 2.0f * tz) * tz * tz;

    int base = (ix * S + iy) * S + iz;
    const float4* p0 = V + base;
    const float4* p1 = p0 + S * S;

    float4 c000 = p0[0];
    float4 c001 = p0[1];
    float4 c010 = p0[S];
    float4 c011 = p0[S + 1];
    float4 c100 = p1[0];
    float4 c101 = p1[1];
    float4 c110 = p1[S];
    float4 c111 = p1[S + 1];

    float4 m00 = lerp4(c000, c100, wx);
    float4 m01 = lerp4(c001, c101, wx);
    float4 m10 = lerp4(c010, c110, wx);
    float4 m11 = lerp4(c011, c111, wx);
    float4 n0  = lerp4(m00, m10, wy);
    float4 n1  = lerp4(m01, m11, wy);
    return lerp4(n0, n1, wz);
}

__device__ __forceinline__ float4 composite(const float4* __restrict__ V16,
                                            const float4* __restrict__ V32,
                                            const float4* __restrict__ V64,
                                            const float4* __restrict__ V128,
                                            float px, float py, float pz) {
    float4 acc = level_val<16>(V16, px, py, pz);
    float4 v;
    v = level_val<32>(V32, px, py, pz);
    acc.x += 0.5f * v.x; acc.y += 0.5f * v.y; acc.z += 0.5f * v.z; acc.w += 0.5f * v.w;
    v = level_val<64>(V64, px, py, pz);
    acc.x += 0.25f * v.x; acc.y += 0.25f * v.y; acc.z += 0.25f * v.z; acc.w += 0.25f * v.w;
    v = level_val<128>(V128, px, py, pz);
    acc.x += 0.125f * v.x; acc.y += 0.125f * v.y; acc.z += 0.125f * v.z; acc.w += 0.125f * v.w;
    return acc;
}

// Main gather over sorted points. XCD-contiguous swizzle: XCD k (bid&7) gets
// a contiguous sorted (spatial) range. If permuted!=0 write tmp[j] coalesced,
// else scatter to out[orig].
__global__ void __launch_bounds__(256)
cvn_main(const float4* __restrict__ sorted,
         const float4* __restrict__ V16, const float4* __restrict__ V32,
         const float4* __restrict__ V64, const float4* __restrict__ V128,
         float4* __restrict__ outbuf, int n, int nblocks, int permuted) {
    int nb8 = nblocks >> 3;
    int c = (blockIdx.x & 7) * nb8 + (blockIdx.x >> 3);
    int j = c * 256 + (int)threadIdx.x;
    if (j >= n) return;
    float4 p = sorted[j];
    float4 acc = composite(V16, V32, V64, V128, p.x, p.y, p.z);
    if (permuted) outbuf[j] = acc;
    else outbuf[__float_as_int(p.w)] = acc;
}

__global__ void __launch_bounds__(256)
cvn_permute(const float4* __restrict__ tmp, const int* __restrict__ rank,
            float4* __restrict__ out, int n) {
    int i = blockIdx.x * 256 + (int)threadIdx.x;
    if (i >= n) return;
    out[i] = tmp[rank[i]];
}

// Fallback: direct unsorted kernel.
__global__ void __launch_bounds__(256)
cvn_direct(const float* __restrict__ x,
           const float4* __restrict__ V16, const float4* __restrict__ V32,
           const float4* __restrict__ V64, const float4* __restrict__ V128,
           float4* __restrict__ out, int n) {
    int i = blockIdx.x * blockDim.x + threadIdx.x;
    if (i >= n) return;
    out[i] = composite(V16, V32, V64, V128, x[3 * i], x[3 * i + 1], x[3 * i + 2]);
}

extern "C" void kernel_launch(void* const* d_in, const int* in_sizes, int n_in,
                              void* d_out, int out_size, void* d_ws, size_t ws_size,
                              hipStream_t stream) {
    const float*  x    = (const float*)d_in[0];
    const float4* V16  = (const float4*)d_in[1];
    const float4* V32  = (const float4*)d_in[2];
    const float4* V64  = (const float4*)d_in[3];
    const float4* V128 = (const float4*)d_in[4];
    float4* out = (float4*)d_out;

    int n = in_sizes[0] / 3;
    int nblk = (n + PTS_PER_BLK - 1) / PTS_PER_BLK;

    auto align256 = [](size_t v) { return (v + 255) & ~(size_t)255; };
    size_t offP      = 0;
    size_t offT      = align256(offP + (size_t)nblk * BUCKETS * sizeof(int));
    size_t offSorted = align256(offT + BUCKETS * sizeof(int));
    size_t offRank   = align256(offSorted + (size_t)n * sizeof(float4));
    size_t offTmp    = align256(offRank + (size_t)n * sizeof(int));
    size_t needFull  = offTmp + (size_t)n * sizeof(float4);
    size_t needMid   = offRank;   // P + T + sorted only

    int grid256 = (n + 255) / 256;
    int nblocks = ((grid256 + 7) / 8) * 8;   // padded for XCD swizzle

    if (ws_size >= needMid) {
        int*    P      = (int*)((char*)d_ws + offP);
        int*    T      = (int*)((char*)d_ws + offT);
        float4* sorted = (float4*)((char*)d_ws + offSorted);
        bool full = (ws_size >= needFull);
        int*    rank = full ? (int*)((char*)d_ws + offRank) : nullptr;
        float4* tmp  = full ? (float4*)((char*)d_ws + offTmp) : nullptr;

        cvn_hist<<<nblk, H_THREADS, 0, stream>>>(x, P, n);
        cvn_colscan<<<BUCKETS / 256, 256, 0, stream>>>(P, T, nblk);
        cvn_totscan<<<1, 256, 0, stream>>>(T);
        cvn_scatter<<<nblk, SC_THREADS, 0, stream>>>(x, P, T, sorted, rank, n,
                                                     full ? 1 : 0);
        cvn_main<<<nblocks, 256, 0, stream>>>(sorted, V16, V32, V64, V128,
                                              full ? tmp : out, n, nblocks,
                                              full ? 1 : 0);
        if (full)
            cvn_permute<<<grid256, 256, 0, stream>>>(tmp, rank, out, n);
    } else {
        cvn_direct<<<grid256, 256, 0, stream>>>(x, V16, V32, V64, V128, out, n);
    }
}

// Round 4
// 258.466 us; speedup vs baseline: 1.7908x; 1.3536x over previous
//
#include <hip/hip_runtime.h>

// CompositeValueNoise R4: 8^3=512-bucket counting sort, fully parallel scan,
// coalesced-run scatter (8 pts/bucket/block -> 128B runs), L2-resident main
// gathers, inverse-permute epilogue (random reads, coalesced writes).

#define NB 512                 // 8^3 buckets
#define PTS_PER_BLK 4096
#define CHUNK 32               // blocks per scan chunk
#define SC_THREADS 1024
#define SC_PPT (PTS_PER_BLK / SC_THREADS)   // 4
#define H_THREADS 256
#define H_PPT (PTS_PER_BLK / H_THREADS)     // 16

__device__ __forceinline__ int bucket_of(float px, float py, float pz) {
    int ix = min(max((int)(px * 8.0f), 0), 7);
    int iy = min(max((int)(py * 8.0f), 0), 7);
    int iz = min(max((int)(pz * 8.0f), 0), 7);
    return (ix * 8 + iy) * 8 + iz;
}

__global__ void __launch_bounds__(H_THREADS)
cvn_hist(const float* __restrict__ x, int* __restrict__ P, int n) {
    __shared__ int cnt[NB];
    int t = threadIdx.x;
    for (int q = t; q < NB; q += H_THREADS) cnt[q] = 0;
    __syncthreads();
    int base = blockIdx.x * PTS_PER_BLK;
    for (int k = 0; k < H_PPT; ++k) {
        int i = base + k * H_THREADS + t;
        if (i < n)
            atomicAdd(&cnt[bucket_of(x[3 * i], x[3 * i + 1], x[3 * i + 2])], 1);
    }
    __syncthreads();
    int* Pb = P + (size_t)blockIdx.x * NB;
    for (int q = t; q < NB; q += H_THREADS) Pb[q] = cnt[q];
}

// Partial sums: S[c][q] = sum of P[b][q] over chunk c.
__global__ void __launch_bounds__(256)
cvn_scan_a(const int* __restrict__ P, int* __restrict__ S, int nblk) {
    int q = blockIdx.x * 256 + threadIdx.x;     // 0..NB-1
    int c = blockIdx.y;
    int b0 = c * CHUNK, b1 = min(b0 + CHUNK, nblk);
    int s = 0;
    for (int b = b0; b < b1; ++b) s += P[(size_t)b * NB + q];
    S[(size_t)c * NB + q] = s;
}

// Per-bucket exclusive scan over chunks + global bucket scan; leaves
// S[c][q] = Texcl[q] + (exclusive chunk prefix within bucket q).
__global__ void __launch_bounds__(NB)
cvn_scan_b(int* __restrict__ S, int nch) {
    __shared__ int part[NB];
    int t = threadIdx.x;                        // 0..NB-1
    int acc = 0;
    for (int c = 0; c < nch; ++c) {
        int v = S[(size_t)c * NB + t];
        S[(size_t)c * NB + t] = acc;
        acc += v;
    }
    part[t] = acc;                              // bucket total
    __syncthreads();
    for (int off = 1; off < NB; off <<= 1) {
        int v = (t >= off) ? part[t - off] : 0;
        __syncthreads();
        if (t >= off) part[t] += v;
        __syncthreads();
    }
    int texcl = (t == 0) ? 0 : part[t - 1];
    for (int c = 0; c < nch; ++c) S[(size_t)c * NB + t] += texcl;
}

// Apply: P[b][q] <- global base position of (block b, bucket q) entries.
__global__ void __launch_bounds__(256)
cvn_scan_c(int* __restrict__ P, const int* __restrict__ S, int nblk) {
    int q = blockIdx.x * 256 + threadIdx.x;
    int c = blockIdx.y;
    int b0 = c * CHUNK, b1 = min(b0 + CHUNK, nblk);
    int run = S[(size_t)c * NB + q];
    for (int b = b0; b < b1; ++b) {
        int v = P[(size_t)b * NB + q];
        P[(size_t)b * NB + q] = run;
        run += v;
    }
}

__global__ void __launch_bounds__(SC_THREADS)
cvn_scatter(const float* __restrict__ x, const int* __restrict__ P,
            float4* __restrict__ sorted, int* __restrict__ rank,
            int n, int write_rank) {
    __shared__ int cnt[NB];                  // -> block-local exclusive counts
    __shared__ int place[NB];
    __shared__ int Pb[NB];                   // global base per bucket
    __shared__ int sc[NB];
    __shared__ float4 payload[PTS_PER_BLK];  // 64 KB
    __shared__ unsigned short bkt[PTS_PER_BLK];
    int t = threadIdx.x, b = blockIdx.x;
    int base = b * PTS_PER_BLK;
    if (t < NB) {
        cnt[t] = 0; place[t] = 0;
        Pb[t] = P[(size_t)b * NB + t];
    }
    __syncthreads();

    float px[SC_PPT], py[SC_PPT], pz[SC_PPT];
    int qq[SC_PPT];
    #pragma unroll
    for (int k = 0; k < SC_PPT; ++k) {
        int i = base + k * SC_THREADS + t;
        if (i < n) {
            px[k] = x[3 * i]; py[k] = x[3 * i + 1]; pz[k] = x[3 * i + 2];
            qq[k] = bucket_of(px[k], py[k], pz[k]);
            atomicAdd(&cnt[qq[k]], 1);
        } else qq[k] = -1;
    }
    __syncthreads();

    // Block-local exclusive scan of cnt[NB] (first NB threads).
    if (t < NB) sc[t] = cnt[t];
    __syncthreads();
    for (int off = 1; off < NB; off <<= 1) {
        int v = (t < NB && t >= off) ? sc[t - off] : 0;
        __syncthreads();
        if (t < NB && t >= off) sc[t] += v;
        __syncthreads();
    }
    if (t < NB) cnt[t] = (t == 0) ? 0 : sc[t - 1];
    __syncthreads();

    #pragma unroll
    for (int k = 0; k < SC_PPT; ++k) {
        if (qq[k] >= 0) {
            int q = qq[k];
            int lp = atomicAdd(&place[q], 1);
            int slot = cnt[q] + lp;
            int i = base + k * SC_THREADS + t;
            payload[slot] = make_float4(px[k], py[k], pz[k], __int_as_float(i));
            bkt[slot] = (unsigned short)q;
            if (write_rank) rank[i] = Pb[q] + lp;
        }
    }
    __syncthreads();

    int total = min(n - base, PTS_PER_BLK);
    #pragma unroll
    for (int k = 0; k < SC_PPT; ++k) {
        int j = k * SC_THREADS + t;
        if (j < total) {
            int q = bkt[j];
            sorted[Pb[q] + (j - cnt[q])] = payload[j];
        }
    }
}

__device__ __forceinline__ float4 lerp4(float4 a, float4 b, float w) {
    return make_float4(a.x + w * (b.x - a.x),
                       a.y + w * (b.y - a.y),
                       a.z + w * (b.z - a.z),
                       a.w + w * (b.w - a.w));
}

template <int RES>
__device__ __forceinline__ float4 level_val(const float4* __restrict__ V,
                                            float px, float py, float pz) {
    constexpr int S = RES + 1;
    float xs = fmodf(px * (float)RES, (float)RES);
    float ys = fmodf(py * (float)RES, (float)RES);
    float zs = fmodf(pz * (float)RES, (float)RES);
    float fx = floorf(xs), fy = floorf(ys), fz = floorf(zs);
    float tx = xs - fx, ty = ys - fy, tz = zs - fz;
    int ix = (int)fx, iy = (int)fy, iz = (int)fz;

    float wx = (3.0f - 2.0f * tx) * tx * tx;
    float wy = (3.0f - 2.0f * ty) * ty * ty;
    float wz = (3.0f - 2.0f * tz) * tz * tz;

    int base = (ix * S + iy) * S + iz;
    const float4* p0 = V + base;
    const float4* p1 = p0 + S * S;

    float4 c000 = p0[0];
    float4 c001 = p0[1];
    float4 c010 = p0[S];
    float4 c011 = p0[S + 1];
    float4 c100 = p1[0];
    float4 c101 = p1[1];
    float4 c110 = p1[S];
    float4 c111 = p1[S + 1];

    float4 m00 = lerp4(c000, c100, wx);
    float4 m01 = lerp4(c001, c101, wx);
    float4 m10 = lerp4(c010, c110, wx);
    float4 m11 = lerp4(c011, c111, wx);
    float4 n0  = lerp4(m00, m10, wy);
    float4 n1  = lerp4(m01, m11, wy);
    return lerp4(n0, n1, wz);
}

__device__ __forceinline__ float4 composite(const float4* __restrict__ V16,
                                            const float4* __restrict__ V32,
                                            const float4* __restrict__ V64,
                                            const float4* __restrict__ V128,
                                            float px, float py, float pz) {
    float4 acc = level_val<16>(V16, px, py, pz);
    float4 v;
    v = level_val<32>(V32, px, py, pz);
    acc.x += 0.5f * v.x; acc.y += 0.5f * v.y; acc.z += 0.5f * v.z; acc.w += 0.5f * v.w;
    v = level_val<64>(V64, px, py, pz);
    acc.x += 0.25f * v.x; acc.y += 0.25f * v.y; acc.z += 0.25f * v.z; acc.w += 0.25f * v.w;
    v = level_val<128>(V128, px, py, pz);
    acc.x += 0.125f * v.x; acc.y += 0.125f * v.y; acc.z += 0.125f * v.z; acc.w += 0.125f * v.w;
    return acc;
}

// Main gather over sorted points; XCD-contiguous swizzle.
__global__ void __launch_bounds__(256)
cvn_main(const float4* __restrict__ sorted,
         const float4* __restrict__ V16, const float4* __restrict__ V32,
         const float4* __restrict__ V64, const float4* __restrict__ V128,
         float4* __restrict__ outbuf, int n, int nblocks, int permuted) {
    int nb8 = nblocks >> 3;
    int c = (blockIdx.x & 7) * nb8 + (blockIdx.x >> 3);
    int j = c * 256 + (int)threadIdx.x;
    if (j >= n) return;
    float4 p = sorted[j];
    float4 acc = composite(V16, V32, V64, V128, p.x, p.y, p.z);
    if (permuted) outbuf[j] = acc;
    else outbuf[__float_as_int(p.w)] = acc;
}

__global__ void __launch_bounds__(256)
cvn_permute(const float4* __restrict__ tmp, const int* __restrict__ rank,
            float4* __restrict__ out, int n) {
    int i = blockIdx.x * 256 + (int)threadIdx.x;
    if (i >= n) return;
    out[i] = tmp[rank[i]];
}

__global__ void __launch_bounds__(256)
cvn_direct(const float* __restrict__ x,
           const float4* __restrict__ V16, const float4* __restrict__ V32,
           const float4* __restrict__ V64, const float4* __restrict__ V128,
           float4* __restrict__ out, int n) {
    int i = blockIdx.x * blockDim.x + threadIdx.x;
    if (i >= n) return;
    out[i] = composite(V16, V32, V64, V128, x[3 * i], x[3 * i + 1], x[3 * i + 2]);
}

extern "C" void kernel_launch(void* const* d_in, const int* in_sizes, int n_in,
                              void* d_out, int out_size, void* d_ws, size_t ws_size,
                              hipStream_t stream) {
    const float*  x    = (const float*)d_in[0];
    const float4* V16  = (const float4*)d_in[1];
    const float4* V32  = (const float4*)d_in[2];
    const float4* V64  = (const float4*)d_in[3];
    const float4* V128 = (const float4*)d_in[4];
    float4* out = (float4*)d_out;

    int n = in_sizes[0] / 3;
    int nblk = (n + PTS_PER_BLK - 1) / PTS_PER_BLK;
    int nch  = (nblk + CHUNK - 1) / CHUNK;

    auto align256 = [](size_t v) { return (v + 255) & ~(size_t)255; };
    size_t offP      = 0;
    size_t offS      = align256(offP + (size_t)nblk * NB * sizeof(int));
    size_t offSorted = align256(offS + (size_t)nch * NB * sizeof(int));
    size_t offRank   = align256(offSorted + (size_t)n * sizeof(float4));
    size_t offTmp    = align256(offRank + (size_t)n * sizeof(int));
    size_t needFull  = offTmp + (size_t)n * sizeof(float4);
    size_t needMid   = offRank;

    int grid256 = (n + 255) / 256;
    int nblocks = ((grid256 + 7) / 8) * 8;

    if (ws_size >= needMid) {
        int*    P      = (int*)((char*)d_ws + offP);
        int*    S      = (int*)((char*)d_ws + offS);
        float4* sorted = (float4*)((char*)d_ws + offSorted);
        bool full = (ws_size >= needFull);
        int*    rank = full ? (int*)((char*)d_ws + offRank) : nullptr;
        float4* tmp  = full ? (float4*)((char*)d_ws + offTmp) : nullptr;

        cvn_hist<<<nblk, H_THREADS, 0, stream>>>(x, P, n);
        cvn_scan_a<<<dim3(NB / 256, nch), 256, 0, stream>>>(P, S, nblk);
        cvn_scan_b<<<1, NB, 0, stream>>>(S, nch);
        cvn_scan_c<<<dim3(NB / 256, nch), 256, 0, stream>>>(P, S, nblk);
        cvn_scatter<<<nblk, SC_THREADS, 0, stream>>>(x, P, sorted, rank, n,
                                                     full ? 1 : 0);
        cvn_main<<<nblocks, 256, 0, stream>>>(sorted, V16, V32, V64, V128,
                                              full ? tmp : out, n, nblocks,
                                              full ? 1 : 0);
        if (full)
            cvn_permute<<<grid256, 256, 0, stream>>>(tmp, rank, out, n);
    } else {
        cvn_direct<<<grid256, 256, 0, stream>>>(x, V16, V32, V64, V128, out, n);
    }
}